// Round 9
// baseline (45.136 us; speedup 1.0000x reference)
//
#include <hip/hip_runtime.h>
#include <hip/hip_fp16.h>

static constexpr int HD   = 128;   // head dim
static constexpr int HH   = 64;    // height
static constexpr int WW   = 64;    // width
static constexpr int ROWS = 2;     // tile rows per block
static constexpr int BLK  = 512;   // 4 threads per pixel (d-quarters)
static constexpr int HALO = ROWS + 2;     // 4 halo rows
static constexpr int DC   = 16;    // d-planes per chunk
static constexpr int NCH  = HD / DC;      // 8 chunks
static constexpr int PSTR = 8;     // uints per pixel in LDS (16 halves)
static constexpr float SCALE = 0.08838834764831845f;  // 128^-0.5

// fp16 LDS staging: pixel span = 16 halves = 4 units of 4 planes (8B each).
// Unit g of column ws lives at slot g ^ ((ws>>2)&3). A thread's b128 write of
// 8 planes (units 2hg,2hg+1) lands at 16B slot-pair hg^((ws>>3)&1), halves
// swapped iff (ws>>2)&1. Reads (unit qf of column cc at slot qf^((cc>>2)&3))
// are bank-conflict-free per 16-lane group. Structure identical to round 8.
static __device__ __forceinline__ unsigned int pkh(float a, float b) {
  __half2 h = __floats2half2_rn(a, b);
  return *(unsigned int*)&h;
}

__global__ __launch_bounds__(BLK, 4) void natten3_kernel(
    const float* __restrict__ Q, const float* __restrict__ K,
    const float* __restrict__ V, float* __restrict__ O)
{
  __shared__ unsigned int buf[2][HALO * WW * PSTR];   // 2 x 8 KB

  const int tid = threadIdx.x;
  const int qf  = tid & 3;               // d-quarter
  const int px  = tid >> 2;              // 0..127 pixel in tile
  const int w   = px & 63;
  const int pr  = px >> 6;               // tile row 0/1

  // XCD-chunked swizzle: 1024 blocks, 128 consecutive tiles per XCD
  const int bid = blockIdx.x;
  const int swz = (bid & 7) * 128 + (bid >> 3);
  const int b   = swz >> 5;              // image
  const int h0  = (swz & 31) * ROWS;     // tile top row
  const int hh  = h0 + pr;

  const int plane = HH * WW;             // 4096
  const size_t img = (size_t)HD * plane;
  const float* Qb = Q + (size_t)b * img;
  const float* Kb = K + (size_t)b * img;
  const float* Vb = V + (size_t)b * img;
  const int qoff = hh * WW + w;
  const int dq   = 4 * qf;

  // staging map: 512 write-groups = 4 halo rows x 64 ws x 2 half-groups, 1/thread
  const int ws    = tid & 63;
  const int rest  = tid >> 6;            // 0..7
  const int is    = rest >> 1;           // halo row 0..3
  const int hg    = rest & 1;            // planes hg*8 .. hg*8+7
  const int grow  = min(max(h0 - 1 + is, 0), HH - 1);
  const int sgg   = grow * WW + ws;      // + (c*DC + hg*8 + p)*plane
  const int sglu  = (is * WW + ws) * PSTR + 4 * (hg ^ ((ws >> 3) & 1));
  const bool sswp = (ws >> 2) & 1;
  const int dstg  = hg * 8;

  // neighbor LDS offsets (uint units, swizzled) + validity masks
  int   lofs[9];
  float msk[9];
  #pragma unroll
  for (int dh = 0; dh < 3; ++dh) {
    #pragma unroll
    for (int dw = 0; dw < 3; ++dw) {
      const int j = dh * 3 + dw;
      const int r = hh + dh - 1, c = w + dw - 1;
      msk[j] = (r >= 0 && r < HH && c >= 0 && c < WW) ? 1.0f : 0.0f;
      const int cc = min(max(c, 0), WW - 1);
      lofs[j] = ((pr + dh) * WW + cc) * PSTR + 2 * (qf ^ ((cc >> 2) & 3));
    }
  }

  // ================= Phase 1: logits =================
  {
    float s[8];
    #pragma unroll
    for (int p = 0; p < 8; ++p) s[p] = Kb[(dstg + p) * plane + sgg];
    const unsigned int ua = pkh(s[0], s[1]), ub = pkh(s[2], s[3]);
    const unsigned int uc = pkh(s[4], s[5]), ud = pkh(s[6], s[7]);
    *(uint4*)&buf[0][sglu] = sswp ? make_uint4(uc, ud, ua, ub)
                                  : make_uint4(ua, ub, uc, ud);
  }
  float q[4];
  #pragma unroll
  for (int p = 0; p < 4; ++p) q[p] = Qb[(dq + p) * plane + qoff];
  __syncthreads();

  float logit[9];
  #pragma unroll
  for (int j = 0; j < 9; ++j) logit[j] = 0.0f;

  for (int c = 0; c < NCH; ++c) {
    const int cur = c & 1;
    float s[8], qn[4];
    if (c + 1 < NCH) {                   // issue next chunk's loads early
      const int dbase = (c + 1) * DC * plane;
      #pragma unroll
      for (int p = 0; p < 8; ++p) s[p] = Kb[dbase + (dstg + p) * plane + sgg];
      #pragma unroll
      for (int p = 0; p < 4; ++p)
        qn[p] = Qb[((c + 1) * DC + dq + p) * plane + qoff];
    }
    const unsigned int* __restrict__ bc = buf[cur];
    #pragma unroll
    for (int j = 0; j < 9; ++j) {
      const uint2 r = *(const uint2*)&bc[lofs[j]];
      const float2 f01 = __half22float2(*(const __half2*)&r.x);
      const float2 f23 = __half22float2(*(const __half2*)&r.y);
      float acc = logit[j];
      acc = fmaf(q[0], f01.x, acc); acc = fmaf(q[1], f01.y, acc);
      acc = fmaf(q[2], f23.x, acc); acc = fmaf(q[3], f23.y, acc);
      logit[j] = acc;
    }
    if (c + 1 < NCH) {
      const unsigned int ua = pkh(s[0], s[1]), ub = pkh(s[2], s[3]);
      const unsigned int uc = pkh(s[4], s[5]), ud = pkh(s[6], s[7]);
      *(uint4*)&buf[cur ^ 1][sglu] = sswp ? make_uint4(uc, ud, ua, ub)
                                          : make_uint4(ua, ub, uc, ud);
      #pragma unroll
      for (int p = 0; p < 4; ++p) q[p] = qn[p];
    }
    __syncthreads();
  }

  // issue V chunk-0 staging loads now; softmax math hides their latency
  float vs[8];
  #pragma unroll
  for (int p = 0; p < 8; ++p) vs[p] = Vb[(dstg + p) * plane + sgg];

  // quad-reduce partial logits (lanes 4m..4m+3 share a pixel)
  #pragma unroll
  for (int j = 0; j < 9; ++j) {
    logit[j] += __shfl_xor(logit[j], 1);
    logit[j] += __shfl_xor(logit[j], 2);
  }
  // softmax over 9 (OOB logits = 0 participate in denominator)
  #pragma unroll
  for (int j = 0; j < 9; ++j) logit[j] = msk[j] * logit[j] * SCALE;
  float m = logit[0];
  #pragma unroll
  for (int j = 1; j < 9; ++j) m = fmaxf(m, logit[j]);
  float att[9];
  float Z = 0.0f;
  #pragma unroll
  for (int j = 0; j < 9; ++j) { att[j] = __expf(logit[j] - m); Z += att[j]; }
  const float rZ = 1.0f / Z;
  #pragma unroll
  for (int j = 0; j < 9; ++j) att[j] *= rZ * msk[j];

  // ================= Phase 2: PV =================
  // buf[0] reads finished at phase-1's final barrier; stage V chunk 0
  {
    const unsigned int ua = pkh(vs[0], vs[1]), ub = pkh(vs[2], vs[3]);
    const unsigned int uc = pkh(vs[4], vs[5]), ud = pkh(vs[6], vs[7]);
    *(uint4*)&buf[0][sglu] = sswp ? make_uint4(uc, ud, ua, ub)
                                  : make_uint4(ua, ub, uc, ud);
  }
  __syncthreads();

  const size_t obase = ((size_t)b * plane + (size_t)h0 * WW) * HD;
  float oprev[4];
  for (int c = 0; c < NCH; ++c) {
    const int cur = c & 1;
    float s[8];
    if (c + 1 < NCH) {
      const int dbase = (c + 1) * DC * plane;
      #pragma unroll
      for (int p = 0; p < 8; ++p) s[p] = Vb[dbase + (dstg + p) * plane + sgg];
    }
    float o0 = 0.f, o1 = 0.f, o2 = 0.f, o3 = 0.f;
    const unsigned int* __restrict__ bc = buf[cur];
    #pragma unroll
    for (int j = 0; j < 9; ++j) {
      const uint2 r = *(const uint2*)&bc[lofs[j]];
      const float2 f01 = __half22float2(*(const __half2*)&r.x);
      const float2 f23 = __half22float2(*(const __half2*)&r.y);
      const float a = att[j];
      o0 = fmaf(a, f01.x, o0); o1 = fmaf(a, f01.y, o1);
      o2 = fmaf(a, f23.x, o2); o3 = fmaf(a, f23.y, o3);
    }
    if (c & 1) {
      // paired writeout: quad covers one full 128B sector of its pixel
      const size_t oa = obase + (size_t)px * HD + (size_t)(c - 1) * DC + dq;
      *(float4*)&O[oa]      = make_float4(oprev[0], oprev[1], oprev[2], oprev[3]);
      *(float4*)&O[oa + DC] = make_float4(o0, o1, o2, o3);
    } else {
      oprev[0] = o0; oprev[1] = o1; oprev[2] = o2; oprev[3] = o3;
    }
    if (c + 1 < NCH) {
      const unsigned int ua = pkh(s[0], s[1]), ub = pkh(s[2], s[3]);
      const unsigned int uc = pkh(s[4], s[5]), ud = pkh(s[6], s[7]);
      *(uint4*)&buf[cur ^ 1][sglu] = sswp ? make_uint4(uc, ud, ua, ub)
                                          : make_uint4(ua, ub, uc, ud);
      __syncthreads();
    }
  }
}

extern "C" void kernel_launch(void* const* d_in, const int* in_sizes, int n_in,
                              void* d_out, int out_size, void* d_ws, size_t ws_size,
                              hipStream_t stream) {
  const float* q = (const float*)d_in[0];
  const float* k = (const float*)d_in[1];
  const float* v = (const float*)d_in[2];
  float* o = (float*)d_out;
  const int nblocks = 32 * (HH / ROWS);   // 1024
  natten3_kernel<<<dim3(nblocks), dim3(BLK), 0, stream>>>(q, k, v, o);
}